// Round 1
// baseline (2506.755 us; speedup 1.0000x reference)
//
#include <hip/hip_runtime.h>

#define NSTEP 512
#define BT 16      // batch tile per workgroup
#define KL 56      // Whh k-columns staged in LDS
#define KR 8       // Whh k-columns kept in registers (64-KL)

__device__ __forceinline__ float sig_(float v) {
    return 1.0f / (1.0f + __expf(-v));
}
__device__ __forceinline__ float tanh_(float v) {
    v = fminf(fmaxf(v, -15.0f), 15.0f);
    float e = __expf(2.0f * v);
    return (e - 1.0f) / (e + 1.0f);
}

// Thread map (256 threads): j = t&63 (hidden unit), bg = t>>6 (batch quad).
// LDS A[row][16]: rows 0..19 = relu-embedded token, rows 20..83 = h.
// Gates (PyTorch order): rows r of the 256-row gate matrix: i=j, f=64+j, g=128+j, o=192+j.
__global__ __launch_bounds__(256, 1) void lstm_fused_kernel(
    const float* __restrict__ x,     const float* __restrict__ Wemb,
    const float* __restrict__ Wih1,  const float* __restrict__ Whh1,
    const float* __restrict__ b1,    const float* __restrict__ Wih2,
    const float* __restrict__ b2,    const float* __restrict__ Wout,
    const float* __restrict__ bout,  float* __restrict__ out)
{
    __shared__ __align__(16) float A[84 * BT];          // 5376 B
    __shared__ __align__(16) float whh4[KL * 64 * 4];   // 57344 B, [k][j][gate]
    __shared__ float We[40];                            // [e][2]

    const int t  = threadIdx.x;
    const int j  = t & 63;
    const int bg = t >> 6;
    const int b0 = blockIdx.x * BT;

    // ---- one-time loads -------------------------------------------------
    if (t < 40) We[t] = Wemb[t];
    for (int idx = t; idx < KL * 64 * 4; idx += 256) {
        int g = idx & 3, j2 = (idx >> 2) & 63, k = idx >> 8;
        whh4[idx] = Whh1[((g << 6) | j2) * 64 + k];
    }
    float wih_r[20][4];
    #pragma unroll
    for (int e = 0; e < 20; ++e)
        #pragma unroll
        for (int g = 0; g < 4; ++g) wih_r[e][g] = Wih1[((g << 6) | j) * 20 + e];
    float whh_r[KR][4];
    #pragma unroll
    for (int k = 0; k < KR; ++k)
        #pragma unroll
        for (int g = 0; g < 4; ++g) whh_r[k][g] = Whh1[((g << 6) | j) * 64 + KL + k];
    float bias[4];
    #pragma unroll
    for (int g = 0; g < 4; ++g) bias[g] = b1[(g << 6) | j];

    // ---- init A: h rows = 0; emb rows from token 0 ----------------------
    float4* A4 = (float4*)A;
    A4[(20 + j) * 4 + bg] = make_float4(0.f, 0.f, 0.f, 0.f);

    const int eb = t >> 4;   // emb-writer role: batch 0..15
    const int ei = t & 15;   // emb-writer role: embed dim 0..15 (+16..19 if ei<4)
    const float* xrow = x + (size_t)(b0 + eb) * (2 * NSTEP);
    __syncthreads();         // We + whh4 staged
    {
        float x0 = xrow[0], x1 = xrow[1];
        A[ei * BT + eb] = fmaxf(x0 * We[ei * 2] + x1 * We[ei * 2 + 1], 0.f);
        if (ei < 4) {
            int e2 = 16 + ei;
            A[e2 * BT + eb] = fmaxf(x0 * We[e2 * 2] + x1 * We[e2 * 2 + 1], 0.f);
        }
    }
    __syncthreads();

    // ---- main recurrence -------------------------------------------------
    float c[4] = {0.f, 0.f, 0.f, 0.f};
    float h[4];
    const float4* W4 = (const float4*)whh4;

    for (int step = 0; step < NSTEP; ++step) {
        // prefetch next token (latency hidden behind the dot products)
        int nxt = (step + 1 < NSTEP) ? (step + 1) : (NSTEP - 1);
        float xa = xrow[2 * nxt], xb = xrow[2 * nxt + 1];

        float acc[4][4];   // [gate][bi]
        #pragma unroll
        for (int g = 0; g < 4; ++g)
            #pragma unroll
            for (int bi = 0; bi < 4; ++bi) acc[g][bi] = bias[g];

        // input (emb) contribution: register weights, broadcast A reads
        #pragma unroll
        for (int e = 0; e < 20; ++e) {
            float4 a = A4[e * 4 + bg];
            #pragma unroll
            for (int g = 0; g < 4; ++g) {
                acc[g][0] += wih_r[e][g] * a.x;
                acc[g][1] += wih_r[e][g] * a.y;
                acc[g][2] += wih_r[e][g] * a.z;
                acc[g][3] += wih_r[e][g] * a.w;
            }
        }
        // recurrent contribution: LDS weights (k<KL)
        #pragma unroll 8
        for (int k = 0; k < KL; ++k) {
            float4 a = A4[(20 + k) * 4 + bg];
            float4 w = W4[k * 64 + j];
            acc[0][0] += w.x * a.x; acc[0][1] += w.x * a.y; acc[0][2] += w.x * a.z; acc[0][3] += w.x * a.w;
            acc[1][0] += w.y * a.x; acc[1][1] += w.y * a.y; acc[1][2] += w.y * a.z; acc[1][3] += w.y * a.w;
            acc[2][0] += w.z * a.x; acc[2][1] += w.z * a.y; acc[2][2] += w.z * a.z; acc[2][3] += w.z * a.w;
            acc[3][0] += w.w * a.x; acc[3][1] += w.w * a.y; acc[3][2] += w.w * a.z; acc[3][3] += w.w * a.w;
        }
        // recurrent tail: register weights (k>=KL)
        #pragma unroll
        for (int k = 0; k < KR; ++k) {
            float4 a = A4[(20 + KL + k) * 4 + bg];
            #pragma unroll
            for (int g = 0; g < 4; ++g) {
                acc[g][0] += whh_r[k][g] * a.x;
                acc[g][1] += whh_r[k][g] * a.y;
                acc[g][2] += whh_r[k][g] * a.z;
                acc[g][3] += whh_r[k][g] * a.w;
            }
        }
        // activations: c,h update (i,f,g,o)
        #pragma unroll
        for (int bi = 0; bi < 4; ++bi) {
            float ig = sig_(acc[0][bi]);
            float fg = sig_(acc[1][bi]);
            float gg = tanh_(acc[2][bi]);
            float og = sig_(acc[3][bi]);
            c[bi] = fg * c[bi] + ig * gg;
            h[bi] = og * tanh_(c[bi]);
        }

        __syncthreads();   // everyone done reading A
        // write h for next step
        A4[(20 + j) * 4 + bg] = make_float4(h[0], h[1], h[2], h[3]);
        // write emb for next step
        float e0 = fmaxf(xa * We[ei * 2] + xb * We[ei * 2 + 1], 0.f);
        A[ei * BT + eb] = e0;
        if (ei < 4) {
            int e2 = 16 + ei;
            A[e2 * BT + eb] = fmaxf(xa * We[e2 * 2] + xb * We[e2 * 2 + 1], 0.f);
        }
        __syncthreads();   // A ready
    }

    // ---- LSTM2 (single step, h=c=0 -> f-gate irrelevant) ----------------
    // thread t = H2 unit u; gate rows: i=u, g=512+u, o=768+u
    const int u = t;
    float acci[BT], accg[BT], acco[BT];
    #pragma unroll
    for (int b = 0; b < BT; ++b) {
        acci[b] = b2[u]; accg[b] = b2[512 + u]; acco[b] = b2[768 + u];
    }
    for (int k = 0; k < 64; ++k) {
        float wi = Wih2[u * 64 + k];
        float wg = Wih2[(512 + u) * 64 + k];
        float wo = Wih2[(768 + u) * 64 + k];
        const float* Ah = &A[(20 + k) * BT];
        #pragma unroll
        for (int b = 0; b < BT; ++b) {
            float hb = Ah[b];
            acci[b] += wi * hb; accg[b] += wg * hb; acco[b] += wo * hb;
        }
    }
    float h2v[BT];
    #pragma unroll
    for (int b = 0; b < BT; ++b) {
        float c2 = sig_(acci[b]) * tanh_(accg[b]);
        h2v[b]   = sig_(acco[b]) * tanh_(c2);
    }

    // ---- output projection: out[b][o] = sum_u h2[u][b]*Wout[o][u] -------
    __syncthreads();                  // done with whh4 region
    float* h2s  = whh4;               // [u][16]
    float* part = whh4 + 256 * BT;    // [grp][b][2]
    #pragma unroll
    for (int b = 0; b < BT; ++b) h2s[u * BT + b] = h2v[b];
    __syncthreads();
    {
        int b = t & 15, grp = t >> 4;
        float p0 = 0.f, p1 = 0.f;
        for (int uu = grp * 16; uu < grp * 16 + 16; ++uu) {
            float hv = h2s[uu * BT + b];
            p0 += hv * Wout[uu];
            p1 += hv * Wout[256 + uu];
        }
        part[(grp * 16 + b) * 2 + 0] = p0;
        part[(grp * 16 + b) * 2 + 1] = p1;
    }
    __syncthreads();
    if (t < 32) {
        int b = t >> 1, o = t & 1;
        float s0 = bout[o];
        for (int grp = 0; grp < 16; ++grp) s0 += part[(grp * 16 + b) * 2 + o];
        out[(size_t)(b0 + b) * 2 + o] = s0;
    }
}

extern "C" void kernel_launch(void* const* d_in, const int* in_sizes, int n_in,
                              void* d_out, int out_size, void* d_ws, size_t ws_size,
                              hipStream_t stream) {
    const float* x    = (const float*)d_in[0];
    const float* Wemb = (const float*)d_in[1];
    const float* Wih1 = (const float*)d_in[2];
    const float* Whh1 = (const float*)d_in[3];
    const float* b1   = (const float*)d_in[4];
    const float* Wih2 = (const float*)d_in[5];
    // d_in[6] = Whh2: unused (h=c=0 at LSTM2's single step)
    const float* b2   = (const float*)d_in[7];
    const float* Wout = (const float*)d_in[8];
    const float* bout = (const float*)d_in[9];
    float* out = (float*)d_out;

    lstm_fused_kernel<<<256, 256, 0, stream>>>(
        x, Wemb, Wih1, Whh1, b1, Wih2, b2, Wout, bout, out);
}

// Round 2
// 1547.295 us; speedup vs baseline: 1.6201x; 1.6201x over previous
//
#include <hip/hip_runtime.h>

#define NSTEP 512
#define BT 8        // batch tile per workgroup
#define KL 40       // Whh k-columns staged in LDS
#define KR 24       // Whh k-columns kept in registers (64-KL)
#define AS 88       // Acol row stride in floats (84 rows + pad, mult of 4)

__device__ __forceinline__ float sig_(float v) {
    return 1.0f / (1.0f + __expf(-v));
}
__device__ __forceinline__ float tanh_(float v) {
    v = fminf(fmaxf(v, -15.0f), 15.0f);
    float e = __expf(2.0f * v);
    return (e - 1.0f) / (e + 1.0f);
}

// Thread map (256 threads = 4 waves): j = t&63 (hidden unit), bg = t>>6 (batch PAIR).
// Each thread: 4 gates x 2 batch. Acol[buf][b][k-row]: rows 0..19 emb, 20..83 h.
// All Acol reads are wave-broadcast float4s over k (bg is wave-uniform).
__global__ __launch_bounds__(256, 2) void lstm_fused_kernel(
    const float* __restrict__ x,     const float* __restrict__ Wemb,
    const float* __restrict__ Wih1,  const float* __restrict__ Whh1,
    const float* __restrict__ b1,    const float* __restrict__ Wih2,
    const float* __restrict__ b2,    const float* __restrict__ Wout,
    const float* __restrict__ bout,  float* __restrict__ out)
{
    __shared__ __align__(16) float Acol[2][BT][AS];     // 5632 B, double-buffered
    __shared__ __align__(16) float whh4[KL * 64 * 4];   // 40960 B, [k][j][gate]
    __shared__ float We[40];                            // [e][2]
    __shared__ __align__(16) float h2s[256 * BT];       // 8192 B (epilogue)
    __shared__ float part[32 * BT * 2];                 // 2048 B (epilogue)

    const int t  = threadIdx.x;
    const int j  = t & 63;
    const int bg = t >> 6;          // batch pair index 0..3
    const int b0 = blockIdx.x * BT;

    // ---- one-time staging ----------------------------------------------
    if (t < 40) We[t] = Wemb[t];
    for (int idx = t; idx < KL * 64 * 4; idx += 256) {
        int g = idx & 3, j2 = (idx >> 2) & 63, k = idx >> 8;
        whh4[idx] = Whh1[((g << 6) | j2) * 64 + k];
    }
    float wih_r[20][4];
    #pragma unroll
    for (int e = 0; e < 20; ++e)
        #pragma unroll
        for (int g = 0; g < 4; ++g) wih_r[e][g] = Wih1[((g << 6) | j) * 20 + e];
    float whh_r[KR][4];
    #pragma unroll
    for (int k = 0; k < KR; ++k)
        #pragma unroll
        for (int g = 0; g < 4; ++g) whh_r[k][g] = Whh1[((g << 6) | j) * 64 + KL + k];
    float bias[4];
    #pragma unroll
    for (int g = 0; g < 4; ++g) bias[g] = b1[(g << 6) | j];

    // ---- init Acol[0]: h rows zero, emb rows from token 0 ---------------
    for (int idx = t; idx < BT * 64; idx += 256) {
        int b = idx >> 6, jj = idx & 63;
        Acol[0][b][20 + jj] = 0.f;
    }
    const int ei = t >> 3;   // emb-writer: embed dim 0..31 (active <20)
    const int eb = t & 7;    // emb-writer: batch 0..7
    const float* xrow = x + (size_t)(b0 + eb) * (2 * NSTEP);
    if (ei < 20) {
        float x0 = xrow[0], x1 = xrow[1];
        Acol[0][eb][ei] = fmaxf(x0 * We[ei * 2] + x1 * We[ei * 2 + 1], 0.f);
    }
    __syncthreads();

    // ---- main recurrence -------------------------------------------------
    float c[2] = {0.f, 0.f};
    const float4* W4 = (const float4*)whh4;
    int cur = 0;

    for (int step = 0; step < NSTEP; ++step) {
        // prefetch next token early (hidden behind the dot products)
        int nxt = (step + 1 < NSTEP) ? (step + 1) : (NSTEP - 1);
        float xa = 0.f, xb = 0.f;
        if (ei < 20) { xa = xrow[2 * nxt]; xb = xrow[2 * nxt + 1]; }

        const float* Ab0 = &Acol[cur][2 * bg][0];
        const float* Ab1 = &Acol[cur][2 * bg + 1][0];

        float acc[4][2];   // [gate][batch 0/1]
        #pragma unroll
        for (int g = 0; g < 4; ++g) { acc[g][0] = bias[g]; acc[g][1] = bias[g]; }

        // emb contribution: register weights, broadcast float4 A reads
        #pragma unroll
        for (int e4 = 0; e4 < 20; e4 += 4) {
            float4 a0 = *(const float4*)(Ab0 + e4);
            float4 a1 = *(const float4*)(Ab1 + e4);
            #pragma unroll
            for (int cc = 0; cc < 4; ++cc) {
                float av0 = (&a0.x)[cc], av1 = (&a1.x)[cc];
                #pragma unroll
                for (int g = 0; g < 4; ++g) {
                    acc[g][0] += wih_r[e4 + cc][g] * av0;
                    acc[g][1] += wih_r[e4 + cc][g] * av1;
                }
            }
        }
        // recurrent, LDS-weight part (k < KL)
        #pragma unroll
        for (int k4 = 0; k4 < KL; k4 += 4) {
            float4 a0 = *(const float4*)(Ab0 + 20 + k4);
            float4 a1 = *(const float4*)(Ab1 + 20 + k4);
            #pragma unroll
            for (int cc = 0; cc < 4; ++cc) {
                float4 w = W4[(k4 + cc) * 64 + j];
                float av0 = (&a0.x)[cc], av1 = (&a1.x)[cc];
                acc[0][0] += w.x * av0; acc[0][1] += w.x * av1;
                acc[1][0] += w.y * av0; acc[1][1] += w.y * av1;
                acc[2][0] += w.z * av0; acc[2][1] += w.z * av1;
                acc[3][0] += w.w * av0; acc[3][1] += w.w * av1;
            }
        }
        // recurrent tail, register weights (k >= KL)
        #pragma unroll
        for (int k4 = 0; k4 < KR; k4 += 4) {
            float4 a0 = *(const float4*)(Ab0 + 20 + KL + k4);
            float4 a1 = *(const float4*)(Ab1 + 20 + KL + k4);
            #pragma unroll
            for (int cc = 0; cc < 4; ++cc) {
                float av0 = (&a0.x)[cc], av1 = (&a1.x)[cc];
                #pragma unroll
                for (int g = 0; g < 4; ++g) {
                    acc[g][0] += whh_r[k4 + cc][g] * av0;
                    acc[g][1] += whh_r[k4 + cc][g] * av1;
                }
            }
        }
        // activations (i,f,g,o) -> c,h
        float h[2];
        #pragma unroll
        for (int bi = 0; bi < 2; ++bi) {
            float ig = sig_(acc[0][bi]);
            float fg = sig_(acc[1][bi]);
            float gg = tanh_(acc[2][bi]);
            float og = sig_(acc[3][bi]);
            c[bi] = fg * c[bi] + ig * gg;
            h[bi] = og * tanh_(c[bi]);
        }

        // write next-step A into the other buffer (no barrier needed before)
        float* An0 = &Acol[cur ^ 1][2 * bg][0];
        float* An1 = &Acol[cur ^ 1][2 * bg + 1][0];
        An0[20 + j] = h[0];
        An1[20 + j] = h[1];
        if (ei < 20)
            Acol[cur ^ 1][eb][ei] = fmaxf(xa * We[ei * 2] + xb * We[ei * 2 + 1], 0.f);
        __syncthreads();   // one barrier per step
        cur ^= 1;
    }
    // after 512 swaps, final h lives in Acol[0]

    // ---- LSTM2 (single step, h=c=0 -> f-gate irrelevant) ----------------
    const int u = t;     // H2 unit 0..255; gate rows i=u, g=512+u, o=768+u
    float acci[BT], accg[BT], acco[BT];
    {
        float bi2 = b2[u], bg2 = b2[512 + u], bo2 = b2[768 + u];
        #pragma unroll
        for (int b = 0; b < BT; ++b) { acci[b] = bi2; accg[b] = bg2; acco[b] = bo2; }
    }
    for (int k4 = 0; k4 < 64; k4 += 4) {
        float4 wi = *(const float4*)(Wih2 + (size_t)u * 64 + k4);
        float4 wg = *(const float4*)(Wih2 + (size_t)(512 + u) * 64 + k4);
        float4 wo = *(const float4*)(Wih2 + (size_t)(768 + u) * 64 + k4);
        #pragma unroll
        for (int b = 0; b < BT; ++b) {
            float4 hb = *(const float4*)(&Acol[0][b][20 + k4]);
            acci[b] += wi.x * hb.x + wi.y * hb.y + wi.z * hb.z + wi.w * hb.w;
            accg[b] += wg.x * hb.x + wg.y * hb.y + wg.z * hb.z + wg.w * hb.w;
            acco[b] += wo.x * hb.x + wo.y * hb.y + wo.z * hb.z + wo.w * hb.w;
        }
    }
    #pragma unroll
    for (int b = 0; b < BT; ++b) {
        float c2 = sig_(acci[b]) * tanh_(accg[b]);
        h2s[u * BT + b] = sig_(acco[b]) * tanh_(c2);
    }
    __syncthreads();

    // ---- output projection: out[b][o] = sum_u h2[u][b]*Wout[o][u] + bout -
    {
        int b = t & 7, grp = t >> 3;            // 32 groups of 8 units
        float p0 = 0.f, p1 = 0.f;
        for (int uu = grp * 8; uu < grp * 8 + 8; ++uu) {
            float hv = h2s[uu * BT + b];
            p0 += hv * Wout[uu];
            p1 += hv * Wout[256 + uu];
        }
        part[grp * 16 + b * 2 + 0] = p0;
        part[grp * 16 + b * 2 + 1] = p1;
    }
    __syncthreads();
    if (t < 16) {
        int b = t >> 1, o = t & 1;
        float s0 = bout[o];
        for (int grp = 0; grp < 32; ++grp) s0 += part[grp * 16 + b * 2 + o];
        out[(size_t)(b0 + b) * 2 + o] = s0;
    }
}

extern "C" void kernel_launch(void* const* d_in, const int* in_sizes, int n_in,
                              void* d_out, int out_size, void* d_ws, size_t ws_size,
                              hipStream_t stream) {
    const float* x    = (const float*)d_in[0];
    const float* Wemb = (const float*)d_in[1];
    const float* Wih1 = (const float*)d_in[2];
    const float* Whh1 = (const float*)d_in[3];
    const float* b1   = (const float*)d_in[4];
    const float* Wih2 = (const float*)d_in[5];
    // d_in[6] = Whh2: unused (h=c=0 at LSTM2's single step)
    const float* b2   = (const float*)d_in[7];
    const float* Wout = (const float*)d_in[8];
    const float* bout = (const float*)d_in[9];
    float* out = (float*)d_out;

    lstm_fused_kernel<<<512, 256, 0, stream>>>(
        x, Wemb, Wih1, Whh1, b1, Wih2, b2, Wout, bout, out);
}

// Round 3
// 1043.497 us; speedup vs baseline: 2.4023x; 1.4828x over previous
//
#include <hip/hip_runtime.h>

typedef __bf16 bf16x8 __attribute__((ext_vector_type(8)));
typedef float  f32x4  __attribute__((ext_vector_type(4)));

#define NSTEP 512
#define BT 8        // batches per block
#define KS 96       // Act row length in bf16 elems: 20 emb + 64 h + 12 zero-pad

__device__ __forceinline__ float sig_(float v) {
    return 1.0f / (1.0f + __expf(-v));
}
__device__ __forceinline__ float tanh_(float v) {
    v = fminf(fmaxf(v, -15.0f), 15.0f);
    float e = __expf(2.0f * v);
    return (e - 1.0f) / (e + 1.0f);
}

// 256 threads = 4 waves. Wave w owns hidden units u in [w*16, w*16+16) for all
// 4 gates (gate-tile gt: rows n = gt*64 + w*16 + 0..15 of the 256-row gate matrix).
// MFMA roles: A-op = weights (16 gates x 32 k) from registers, B-op = activations
// (32 k x 16 batch) from LDS. D[i=unit][j=batch]: col=lane&15 (batch), row=(lane>>4)*4+r.
// Precision: bf16-split x3 (Whi*Ahi + Whi*Alo + Wlo*Ahi), fp32 MFMA accumulate.
__global__ __launch_bounds__(256, 2) void lstm_mfma_kernel(
    const float* __restrict__ x,     const float* __restrict__ Wemb,
    const float* __restrict__ Wih1,  const float* __restrict__ Whh1,
    const float* __restrict__ b1,    const float* __restrict__ Wih2,
    const float* __restrict__ b2,    const float* __restrict__ Wout,
    const float* __restrict__ bout,  float* __restrict__ out)
{
    __shared__ __align__(16) __bf16 Act[2][2][16][KS];  // [buf][hi/lo][batchrow][k] = 12288 B
    __shared__ __align__(16) float h2tmp[BT * 64];      // fp32 h64 for epilogue
    __shared__ __align__(16) float h2s[256 * BT];       // h256 for out-proj
    __shared__ float part[32 * BT * 2];

    const int t = threadIdx.x;
    const int l = t & 63;
    const int w = t >> 6;        // wave id 0..3
    const int m = l & 15;        // A-frag row / D col (batch) / B col
    const int q = l >> 4;        // quad 0..3
    const int b0 = blockIdx.x * BT;

    // ---- one-time: weight fragments (bf16 hi/lo) into registers ----------
    // lane holds A_op[row=m][k=q*8+jj] for each (gate-tile, k-chunk)
    bf16x8 wf[4][3][2];
    #pragma unroll
    for (int gt = 0; gt < 4; ++gt) {
        const int n = gt * 64 + (w << 4) + m;   // gate-matrix row
        #pragma unroll
        for (int kc = 0; kc < 3; ++kc) {
            #pragma unroll
            for (int jj = 0; jj < 8; ++jj) {
                int k = kc * 32 + (q << 3) + jj;
                float v = 0.0f;
                if (k < 20)       v = Wih1[n * 20 + k];
                else if (k < 84)  v = Whh1[n * 64 + (k - 20)];
                __bf16 hi = (__bf16)v;
                wf[gt][kc][0][jj] = hi;
                wf[gt][kc][1][jj] = (__bf16)(v - (float)hi);
            }
        }
    }
    float bias[4][4];
    #pragma unroll
    for (int gt = 0; gt < 4; ++gt)
        #pragma unroll
        for (int r = 0; r < 4; ++r)
            bias[gt][r] = b1[gt * 64 + (w << 4) + (q << 2) + r];

    // ---- emb-writer role: thread t<160 handles (batch be, embed dim ee) ---
    const int be_raw = t / 20;
    const int be = be_raw < 8 ? be_raw : 7;
    const int ee = t - be_raw * 20;
    const bool embp = (t < 160);
    const float* xrow = x + (size_t)(b0 + be) * (2 * NSTEP);
    float we0 = 0.f, we1 = 0.f;
    if (embp) { we0 = Wemb[ee * 2]; we1 = Wemb[ee * 2 + 1]; }

    // ---- zero Act (pad rows 8..15, pad k 84..95 stay zero forever) --------
    for (int idx = t; idx < 2 * 2 * 16 * KS; idx += 256)
        ((__bf16*)Act)[idx] = (__bf16)0.0f;
    __syncthreads();
    if (embp) {
        float v = fmaxf(xrow[0] * we0 + xrow[1] * we1, 0.0f);
        __bf16 hh = (__bf16)v;
        Act[0][0][be][ee] = hh;
        Act[0][1][be][ee] = (__bf16)(v - (float)hh);
    }
    __syncthreads();

    // ---- main recurrence --------------------------------------------------
    float cst[4] = {0.f, 0.f, 0.f, 0.f};
    int cur = 0;

    for (int step = 0; step < NSTEP; ++step) {
        // prefetch next token (L2-resident; latency hidden behind MFMA)
        float xa = 0.f, xb = 0.f;
        if (embp) {
            int ns = (step + 1 < NSTEP) ? step + 1 : NSTEP - 1;
            xa = xrow[2 * ns]; xb = xrow[2 * ns + 1];
        }

        // B-operand fragments: lane holds Act[k=kc*32+q*8+jj][batch=m]
        bf16x8 bh[3], bl[3];
        #pragma unroll
        for (int kc = 0; kc < 3; ++kc) {
            bh[kc] = *(const bf16x8*)&Act[cur][0][m][kc * 32 + (q << 3)];
            bl[kc] = *(const bf16x8*)&Act[cur][1][m][kc * 32 + (q << 3)];
        }

        f32x4 acc[4];
        #pragma unroll
        for (int gt = 0; gt < 4; ++gt)
            acc[gt] = (f32x4){bias[gt][0], bias[gt][1], bias[gt][2], bias[gt][3]};

        #pragma unroll
        for (int gt = 0; gt < 4; ++gt) {
            #pragma unroll
            for (int kc = 0; kc < 3; ++kc) {
                acc[gt] = __builtin_amdgcn_mfma_f32_16x16x32_bf16(wf[gt][kc][0], bh[kc], acc[gt], 0, 0, 0);
                acc[gt] = __builtin_amdgcn_mfma_f32_16x16x32_bf16(wf[gt][kc][0], bl[kc], acc[gt], 0, 0, 0);
                acc[gt] = __builtin_amdgcn_mfma_f32_16x16x32_bf16(wf[gt][kc][1], bh[kc], acc[gt], 0, 0, 0);
            }
        }

        // activations: lane owns batch m, units (w*16 + q*4 + r), gates i,f,g,o
        const int nxt = cur ^ 1;
        float hv[4];
        #pragma unroll
        for (int r = 0; r < 4; ++r) {
            float ig = sig_(acc[0][r]);
            float fg = sig_(acc[1][r]);
            float gg = tanh_(acc[2][r]);
            float og = sig_(acc[3][r]);
            cst[r] = fg * cst[r] + ig * gg;
            hv[r]  = og * tanh_(cst[r]);
        }
        if (m < BT) {
            #pragma unroll
            for (int r = 0; r < 4; ++r) {
                int u = (w << 4) + (q << 2) + r;
                __bf16 hh = (__bf16)hv[r];
                Act[nxt][0][m][20 + u] = hh;
                Act[nxt][1][m][20 + u] = (__bf16)(hv[r] - (float)hh);
            }
        }
        if (embp) {
            float v = fmaxf(xa * we0 + xb * we1, 0.0f);
            __bf16 hh = (__bf16)v;
            Act[nxt][0][be][ee] = hh;
            Act[nxt][1][be][ee] = (__bf16)(v - (float)hh);
        }
        __syncthreads();
        cur = nxt;
    }
    // final h (hi/lo) is in Act[cur]

    // ---- epilogue: reconstruct h64 in fp32 --------------------------------
    {
        int idx = t;           // 512 values, 2 per thread
        #pragma unroll
        for (int rep = 0; rep < 2; ++rep) {
            int b = idx >> 6, k = idx & 63;
            h2tmp[idx] = (float)Act[cur][0][b][20 + k] + (float)Act[cur][1][b][20 + k];
            idx += 256;
        }
    }
    __syncthreads();

    // ---- LSTM2 (single step, h=c=0 -> f-gate irrelevant), u = t -----------
    const int u = t;
    float acci[BT], accg[BT], acco[BT];
    {
        float bi2 = b2[u], bg2 = b2[512 + u], bo2 = b2[768 + u];
        #pragma unroll
        for (int b = 0; b < BT; ++b) { acci[b] = bi2; accg[b] = bg2; acco[b] = bo2; }
    }
    for (int k4 = 0; k4 < 64; k4 += 4) {
        float4 wi = *(const float4*)&Wih2[(size_t)u * 64 + k4];
        float4 wg = *(const float4*)&Wih2[(size_t)(512 + u) * 64 + k4];
        float4 wo = *(const float4*)&Wih2[(size_t)(768 + u) * 64 + k4];
        #pragma unroll
        for (int b = 0; b < BT; ++b) {
            float4 hb = *(const float4*)&h2tmp[b * 64 + k4];
            acci[b] += wi.x * hb.x + wi.y * hb.y + wi.z * hb.z + wi.w * hb.w;
            accg[b] += wg.x * hb.x + wg.y * hb.y + wg.z * hb.z + wg.w * hb.w;
            acco[b] += wo.x * hb.x + wo.y * hb.y + wo.z * hb.z + wo.w * hb.w;
        }
    }
    #pragma unroll
    for (int b = 0; b < BT; ++b) {
        float c2 = sig_(acci[b]) * tanh_(accg[b]);
        h2s[u * BT + b] = sig_(acco[b]) * tanh_(c2);
    }
    __syncthreads();

    // ---- output projection ------------------------------------------------
    {
        int b = t & 7, grp = t >> 3;   // 32 groups x 8 units
        float p0 = 0.f, p1 = 0.f;
        for (int uu = grp * 8; uu < grp * 8 + 8; ++uu) {
            float hvv = h2s[uu * BT + b];
            p0 += hvv * Wout[uu];
            p1 += hvv * Wout[256 + uu];
        }
        part[grp * 16 + b * 2 + 0] = p0;
        part[grp * 16 + b * 2 + 1] = p1;
    }
    __syncthreads();
    if (t < 16) {
        int b = t >> 1, o = t & 1;
        float s0 = bout[o];
        for (int grp = 0; grp < 32; ++grp) s0 += part[grp * 16 + b * 2 + o];
        out[(size_t)(b0 + b) * 2 + o] = s0;
    }
}

extern "C" void kernel_launch(void* const* d_in, const int* in_sizes, int n_in,
                              void* d_out, int out_size, void* d_ws, size_t ws_size,
                              hipStream_t stream) {
    const float* x    = (const float*)d_in[0];
    const float* Wemb = (const float*)d_in[1];
    const float* Wih1 = (const float*)d_in[2];
    const float* Whh1 = (const float*)d_in[3];
    const float* b1   = (const float*)d_in[4];
    const float* Wih2 = (const float*)d_in[5];
    // d_in[6] = Whh2: unused (h=c=0 at LSTM2's single step)
    const float* b2   = (const float*)d_in[7];
    const float* Wout = (const float*)d_in[8];
    const float* bout = (const float*)d_in[9];
    float* out = (float*)d_out;

    lstm_mfma_kernel<<<512, 256, 0, stream>>>(
        x, Wemb, Wih1, Whh1, b1, Wih2, b2, Wout, bout, out);
}

// Round 4
// 488.703 us; speedup vs baseline: 5.1294x; 2.1352x over previous
//
#include <hip/hip_runtime.h>

typedef __bf16 bf16x8 __attribute__((ext_vector_type(8)));
typedef __bf16 bf16x4 __attribute__((ext_vector_type(4)));
typedef float  f32x4  __attribute__((ext_vector_type(4)));

#define NSTEP 512
#define BT 16       // batches per block = full MFMA tile width (no pad columns)
#define KS 104      // Act row stride in bf16: 208 B = 52 dw; 52 % 32 = 20 -> m*20 distinct
                    // banks for m=0..7, m<->m+8 2-way (free). Kills the KS=96 8-way conflicts.

// Division-free activations: v_rcp_f32 (<=1 ulp) instead of the div_scale/div_fmas
// sequence fp32 '/' expands to without fast-math.
__device__ __forceinline__ float sig_(float v) {
    return __builtin_amdgcn_rcpf(1.0f + __expf(-v));
}
__device__ __forceinline__ float tanh_(float v) {
    v = fminf(fmaxf(v, -15.0f), 15.0f);
    float e = __expf(2.0f * v);
    return (e - 1.0f) * __builtin_amdgcn_rcpf(e + 1.0f);
}

// 256 threads = 4 waves, grid 256 = 1 block/CU, 16 real batches per block.
// Wave w owns units w*16..w*16+15 for ALL 4 gates (gate-tile gt -> rows gt*64+w*16+m).
// MFMA: A-op = weights (registers, bf16 hi/lo), B-op = activations (LDS).
// D[i=unit][j=batch]: col=lane&15 (batch), row=(lane>>4)*4+r -> all 4 gates of a unit
// in one lane; c-state in registers; 1 barrier/step (double-buffered Act).
__global__ __launch_bounds__(256, 1) void lstm_mfma_kernel(
    const float* __restrict__ x,     const float* __restrict__ Wemb,
    const float* __restrict__ Wih1,  const float* __restrict__ Whh1,
    const float* __restrict__ b1,    const float* __restrict__ Wih2,
    const float* __restrict__ b2,    const float* __restrict__ Wout,
    const float* __restrict__ bout,  float* __restrict__ out)
{
    __shared__ __align__(16) __bf16 Act[2][2][16][KS];  // [buf][hi/lo][batch][k]  13312 B
    __shared__ __align__(16) float h2tmp[BT * 64];      // fp32 h64 for epilogue    4096 B
    __shared__ __align__(16) float h2s[256 * BT];       // h256 for out-proj       16384 B
    __shared__ float part[16 * BT * 2];                 //                          2048 B

    const int t = threadIdx.x;
    const int l = t & 63;
    const int w = t >> 6;        // wave 0..3
    const int m = l & 15;        // batch col / A row / B col
    const int q = l >> 4;        // quad 0..3
    const int b0 = blockIdx.x * BT;

    // ---- one-time: weight fragments (bf16 hi/lo) into registers -----------
    bf16x8 wf[4][3][2];
    #pragma unroll
    for (int gt = 0; gt < 4; ++gt) {
        const int n = gt * 64 + (w << 4) + m;   // gate-matrix row
        #pragma unroll
        for (int kc = 0; kc < 3; ++kc) {
            #pragma unroll
            for (int jj = 0; jj < 8; ++jj) {
                int k = kc * 32 + (q << 3) + jj;
                float v = 0.0f;
                if (k < 20)       v = Wih1[n * 20 + k];
                else if (k < 84)  v = Whh1[n * 64 + (k - 20)];
                __bf16 hi = (__bf16)v;
                wf[gt][kc][0][jj] = hi;
                wf[gt][kc][1][jj] = (__bf16)(v - (float)hi);
            }
        }
    }
    float bias[4][4];
    #pragma unroll
    for (int gt = 0; gt < 4; ++gt)
        #pragma unroll
        for (int r = 0; r < 4; ++r)
            bias[gt][r] = b1[gt * 64 + (w << 4) + (q << 2) + r];

    // ---- emb-writer roles: role1 covers (be=t&15, ee=t>>4) = 16x16;
    //      role2 (t<64) covers ee 16..19.
    const int be = t & 15;
    const int ee = t >> 4;
    const bool emb2 = (t < 64);
    const int ee2 = 16 + (t >> 4);              // valid when emb2
    const float* xrow = x + (size_t)(b0 + be) * (2 * NSTEP);
    const float we0 = Wemb[ee * 2], we1 = Wemb[ee * 2 + 1];
    float we20 = 0.f, we21 = 0.f;
    if (emb2) { we20 = Wemb[ee2 * 2]; we21 = Wemb[ee2 * 2 + 1]; }

    // ---- zero Act (k pads 84..103 + all rows), then emb of token 0 --------
    for (int idx = t; idx < 2 * 2 * 16 * KS; idx += 256)
        ((__bf16*)Act)[idx] = (__bf16)0.0f;
    __syncthreads();
    {
        float x0 = xrow[0], x1 = xrow[1];
        float v1 = fmaxf(x0 * we0 + x1 * we1, 0.0f);
        __bf16 h1 = (__bf16)v1;
        Act[0][0][be][ee] = h1;
        Act[0][1][be][ee] = (__bf16)(v1 - (float)h1);
        if (emb2) {
            float v2 = fmaxf(x0 * we20 + x1 * we21, 0.0f);
            __bf16 h2 = (__bf16)v2;
            Act[0][0][be][ee2] = h2;
            Act[0][1][be][ee2] = (__bf16)(v2 - (float)h2);
        }
    }
    __syncthreads();

    // ---- main recurrence ---------------------------------------------------
    float cst[4] = {0.f, 0.f, 0.f, 0.f};
    int cur = 0;

    for (int step = 0; step < NSTEP; ++step) {
        // prefetch next token (L2-resident; consumed ~end of step)
        int ns = (step + 1 < NSTEP) ? step + 1 : NSTEP - 1;
        float xa = xrow[2 * ns], xb = xrow[2 * ns + 1];

        // B-operand fragments: lane holds Act[hi/lo][batch=m][k=kc*32+q*8+jj]
        bf16x8 bh[3], bl[3];
        #pragma unroll
        for (int kc = 0; kc < 3; ++kc) {
            bh[kc] = *(const bf16x8*)&Act[cur][0][m][kc * 32 + (q << 3)];
            bl[kc] = *(const bf16x8*)&Act[cur][1][m][kc * 32 + (q << 3)];
        }

        f32x4 acc[4];
        #pragma unroll
        for (int gt = 0; gt < 4; ++gt)
            acc[gt] = (f32x4){bias[gt][0], bias[gt][1], bias[gt][2], bias[gt][3]};

        #pragma unroll
        for (int gt = 0; gt < 4; ++gt) {
            #pragma unroll
            for (int kc = 0; kc < 3; ++kc) {
                acc[gt] = __builtin_amdgcn_mfma_f32_16x16x32_bf16(wf[gt][kc][0], bh[kc], acc[gt], 0, 0, 0);
                acc[gt] = __builtin_amdgcn_mfma_f32_16x16x32_bf16(wf[gt][kc][0], bl[kc], acc[gt], 0, 0, 0);
                acc[gt] = __builtin_amdgcn_mfma_f32_16x16x32_bf16(wf[gt][kc][1], bh[kc], acc[gt], 0, 0, 0);
            }
        }

        // activations: lane owns batch m, units w*16+q*4+r, gates i,f,g,o
        const int nxt = cur ^ 1;
        bf16x4 ph, pl;
        #pragma unroll
        for (int r = 0; r < 4; ++r) {
            float ig = sig_(acc[0][r]);
            float fg = sig_(acc[1][r]);
            float gg = tanh_(acc[2][r]);
            float og = sig_(acc[3][r]);
            cst[r] = fg * cst[r] + ig * gg;
            float hv = og * tanh_(cst[r]);
            __bf16 hh = (__bf16)hv;
            ph[r] = hh;
            pl[r] = (__bf16)(hv - (float)hh);
        }
        // packed 8B h writeback: units w*16+q*4..+3 at batch col m
        *(bf16x4*)&Act[nxt][0][m][20 + (w << 4) + (q << 2)] = ph;
        *(bf16x4*)&Act[nxt][1][m][20 + (w << 4) + (q << 2)] = pl;
        // emb for next step
        {
            float v1 = fmaxf(xa * we0 + xb * we1, 0.0f);
            __bf16 h1 = (__bf16)v1;
            Act[nxt][0][be][ee] = h1;
            Act[nxt][1][be][ee] = (__bf16)(v1 - (float)h1);
            if (emb2) {
                float v2 = fmaxf(xa * we20 + xb * we21, 0.0f);
                __bf16 h2 = (__bf16)v2;
                Act[nxt][0][be][ee2] = h2;
                Act[nxt][1][be][ee2] = (__bf16)(v2 - (float)h2);
            }
        }
        __syncthreads();
        cur = nxt;
    }
    // final h (hi/lo) in Act[cur]

    // ---- epilogue: reconstruct h64 in fp32 ---------------------------------
    #pragma unroll
    for (int rep = 0; rep < 4; ++rep) {
        int idx = t + rep * 256;                 // 1024 values
        int b = idx >> 6, k = idx & 63;
        h2tmp[idx] = (float)Act[cur][0][b][20 + k] + (float)Act[cur][1][b][20 + k];
    }
    __syncthreads();

    // ---- LSTM2 (single step, h=c=0 -> f-gate irrelevant), u = t ------------
    const int u = t;
    float acci[BT], accg[BT], acco[BT];
    {
        float bi2 = b2[u], bg2 = b2[512 + u], bo2 = b2[768 + u];
        #pragma unroll
        for (int b = 0; b < BT; ++b) { acci[b] = bi2; accg[b] = bg2; acco[b] = bo2; }
    }
    for (int k4 = 0; k4 < 64; k4 += 4) {
        float4 wi = *(const float4*)&Wih2[(size_t)u * 64 + k4];
        float4 wg = *(const float4*)&Wih2[(size_t)(512 + u) * 64 + k4];
        float4 wo = *(const float4*)&Wih2[(size_t)(768 + u) * 64 + k4];
        #pragma unroll
        for (int b = 0; b < BT; ++b) {
            float4 hb = *(const float4*)&h2tmp[b * 64 + k4];
            acci[b] += wi.x * hb.x + wi.y * hb.y + wi.z * hb.z + wi.w * hb.w;
            accg[b] += wg.x * hb.x + wg.y * hb.y + wg.z * hb.z + wg.w * hb.w;
            acco[b] += wo.x * hb.x + wo.y * hb.y + wo.z * hb.z + wo.w * hb.w;
        }
    }
    #pragma unroll
    for (int b = 0; b < BT; ++b) {
        float c2 = sig_(acci[b]) * tanh_(accg[b]);
        h2s[u * BT + b] = sig_(acco[b]) * tanh_(c2);
    }
    __syncthreads();

    // ---- output projection -------------------------------------------------
    {
        int b = t & 15, grp = t >> 4;            // 16 groups x 16 units
        float p0 = 0.f, p1 = 0.f;
        for (int uu = grp * 16; uu < grp * 16 + 16; ++uu) {
            float hvv = h2s[uu * BT + b];
            p0 += hvv * Wout[uu];
            p1 += hvv * Wout[256 + uu];
        }
        part[(grp * BT + b) * 2 + 0] = p0;
        part[(grp * BT + b) * 2 + 1] = p1;
    }
    __syncthreads();
    if (t < 32) {
        int b = t >> 1, o = t & 1;
        float s0 = bout[o];
        for (int grp = 0; grp < 16; ++grp) s0 += part[(grp * BT + b) * 2 + o];
        out[(size_t)(b0 + b) * 2 + o] = s0;
    }
}

extern "C" void kernel_launch(void* const* d_in, const int* in_sizes, int n_in,
                              void* d_out, int out_size, void* d_ws, size_t ws_size,
                              hipStream_t stream) {
    const float* x    = (const float*)d_in[0];
    const float* Wemb = (const float*)d_in[1];
    const float* Wih1 = (const float*)d_in[2];
    const float* Whh1 = (const float*)d_in[3];
    const float* b1   = (const float*)d_in[4];
    const float* Wih2 = (const float*)d_in[5];
    // d_in[6] = Whh2: unused (h=c=0 at LSTM2's single step)
    const float* b2   = (const float*)d_in[7];
    const float* Wout = (const float*)d_in[8];
    const float* bout = (const float*)d_in[9];
    float* out = (float*)d_out;

    lstm_mfma_kernel<<<256, 256, 0, stream>>>(
        x, Wemb, Wih1, Whh1, b1, Wih2, b2, Wout, bout, out);
}

// Round 5
// 484.008 us; speedup vs baseline: 5.1792x; 1.0097x over previous
//
#include <hip/hip_runtime.h>

typedef __bf16 bf16x8 __attribute__((ext_vector_type(8)));
typedef float  f32x4  __attribute__((ext_vector_type(4)));

#define NSTEP 512
#define BT 16       // batches per block = full MFMA tile width
#define KS 104      // Act row stride in bf16 (52 dw; 52%32=20 -> conflict-benign)

__device__ __forceinline__ float sig_(float v) {
    return __builtin_amdgcn_rcpf(1.0f + __expf(-v));
}
// 1 - 2/(e^{2v}+1): overflow-safe (e^inf -> rcp(inf)=0 -> 1; e^-inf -> rcp(1) -> -1),
// no clamp needed; 2 trans + 3 arith.
__device__ __forceinline__ float tanh_(float v) {
    return 1.0f - 2.0f * __builtin_amdgcn_rcpf(__expf(v + v) + 1.0f);
}

// 512 threads = 8 waves, grid 256 (1 block/CU, 2 waves/SIMD), 16 real batches.
// Gate matrix (256 rows = gate*64+unit) is tiled as 16 MFMA tiles of 16 rows,
// tile tau covering units tau*4..tau*4+3 with tile-row = usub*4 + gate.
// -> A-row m: unit = tau*4 + (m>>2), gate = m&3.
// -> D row q*4+r: unit = tau*4 + q, gate = r  => all 4 gates of a unit in ONE lane
//    (acc[r] = gate r), 1 h per lane per tile. Wave w owns tiles {2w, 2w+1} = 2 h/lane.
// B-op = activations from LDS (same frags for both tiles). 3-pass bf16-split.
__global__ __launch_bounds__(512, 2) void lstm_mfma_kernel(
    const float* __restrict__ x,     const float* __restrict__ Wemb,
    const float* __restrict__ Wih1,  const float* __restrict__ Whh1,
    const float* __restrict__ b1,    const float* __restrict__ Wih2,
    const float* __restrict__ b2,    const float* __restrict__ Wout,
    const float* __restrict__ bout,  float* __restrict__ out)
{
    __shared__ __align__(16) __bf16 Act[2][2][16][KS];  // [buf][hi/lo][batch][k] 13312 B
    __shared__ __align__(16) float h2tmp[BT * 64];      //                        4096 B
    __shared__ __align__(16) float h2s[256 * BT];       //                       16384 B
    __shared__ float part[32 * BT * 2];                 //                        4096 B

    const int t = threadIdx.x;
    const int l = t & 63;
    const int w = t >> 6;        // wave 0..7
    const int m = l & 15;        // tile A-row / B col (batch) / D col
    const int q = l >> 4;        // quad: D rows q*4+r
    const int b0 = blockIdx.x * BT;

    // ---- one-time: weight fragments (bf16 hi/lo) into registers -----------
    bf16x8 wf[2][3][2];
    #pragma unroll
    for (int tt = 0; tt < 2; ++tt) {
        const int ubase = (2 * w + tt) * 4;
        const int n = (m & 3) * 64 + ubase + (m >> 2);   // gate-matrix row
        #pragma unroll
        for (int kc = 0; kc < 3; ++kc) {
            #pragma unroll
            for (int jj = 0; jj < 8; ++jj) {
                int k = kc * 32 + (q << 3) + jj;
                float v = 0.0f;
                if (k < 20)       v = Wih1[n * 20 + k];
                else if (k < 84)  v = Whh1[n * 64 + (k - 20)];
                __bf16 hi = (__bf16)v;
                wf[tt][kc][0][jj] = hi;
                wf[tt][kc][1][jj] = (__bf16)(v - (float)hi);
            }
        }
    }
    // lane's own units: u(tt) = (2w+tt)*4 + q; bias[tt][r] = b1[r*64 + u(tt)]
    float bias[2][4];
    #pragma unroll
    for (int tt = 0; tt < 2; ++tt)
        #pragma unroll
        for (int r = 0; r < 4; ++r)
            bias[tt][r] = b1[r * 64 + (2 * w + tt) * 4 + q];

    // ---- emb-writer role: t<320 covers (be=t&15, ee=t>>4), ee 0..19 --------
    const int be = t & 15;
    const int ee = t >> 4;
    const bool embp = (t < 320);
    const float* xrow = x + (size_t)(b0 + be) * (2 * NSTEP);
    float we0 = 0.f, we1 = 0.f;
    if (embp) { we0 = Wemb[ee * 2]; we1 = Wemb[ee * 2 + 1]; }

    // ---- zero Act (k pads 84..103 stay zero), emb of token 0 ---------------
    for (int idx = t; idx < 2 * 2 * 16 * KS; idx += 512)
        ((__bf16*)Act)[idx] = (__bf16)0.0f;
    __syncthreads();
    if (embp) {
        float x0 = xrow[0], x1 = xrow[1];
        float v1 = fmaxf(x0 * we0 + x1 * we1, 0.0f);
        __bf16 h1 = (__bf16)v1;
        Act[0][0][be][ee] = h1;
        Act[0][1][be][ee] = (__bf16)(v1 - (float)h1);
    }
    __syncthreads();

    // ---- main recurrence ---------------------------------------------------
    float cst[2] = {0.f, 0.f};
    int cur = 0;

    for (int step = 0; step < NSTEP; ++step) {
        // prefetch next token (L2-resident)
        float xa = 0.f, xb = 0.f;
        if (embp) {
            int ns = (step + 1 < NSTEP) ? step + 1 : NSTEP - 1;
            xa = xrow[2 * ns]; xb = xrow[2 * ns + 1];
        }

        // B-frags: lane holds Act[hi/lo][batch=m][k=kc*32+q*8+jj]
        bf16x8 bh[3], bl[3];
        #pragma unroll
        for (int kc = 0; kc < 3; ++kc) {
            bh[kc] = *(const bf16x8*)&Act[cur][0][m][kc * 32 + (q << 3)];
            bl[kc] = *(const bf16x8*)&Act[cur][1][m][kc * 32 + (q << 3)];
        }

        f32x4 acc[2];
        #pragma unroll
        for (int tt = 0; tt < 2; ++tt)
            acc[tt] = (f32x4){bias[tt][0], bias[tt][1], bias[tt][2], bias[tt][3]};

        #pragma unroll
        for (int tt = 0; tt < 2; ++tt) {
            #pragma unroll
            for (int kc = 0; kc < 3; ++kc) {
                acc[tt] = __builtin_amdgcn_mfma_f32_16x16x32_bf16(wf[tt][kc][0], bh[kc], acc[tt], 0, 0, 0);
                acc[tt] = __builtin_amdgcn_mfma_f32_16x16x32_bf16(wf[tt][kc][0], bl[kc], acc[tt], 0, 0, 0);
                acc[tt] = __builtin_amdgcn_mfma_f32_16x16x32_bf16(wf[tt][kc][1], bh[kc], acc[tt], 0, 0, 0);
            }
        }

        // activations: lane owns (unit u(tt), batch m); acc[tt] = {i,f,g,o}
        const int nxt = cur ^ 1;
        #pragma unroll
        for (int tt = 0; tt < 2; ++tt) {
            float ig = sig_(acc[tt][0]);
            float fg = sig_(acc[tt][1]);
            float gg = tanh_(acc[tt][2]);
            float og = sig_(acc[tt][3]);
            cst[tt] = fg * cst[tt] + ig * gg;
            float hv = og * tanh_(cst[tt]);
            __bf16 hh = (__bf16)hv;
            int u = (2 * w + tt) * 4 + q;
            Act[nxt][0][m][20 + u] = hh;
            Act[nxt][1][m][20 + u] = (__bf16)(hv - (float)hh);
        }
        // emb for next step
        if (embp) {
            float v1 = fmaxf(xa * we0 + xb * we1, 0.0f);
            __bf16 h1 = (__bf16)v1;
            Act[nxt][0][be][ee] = h1;
            Act[nxt][1][be][ee] = (__bf16)(v1 - (float)h1);
        }
        __syncthreads();
        cur = nxt;
    }
    // final h (hi/lo) in Act[cur]

    // ---- epilogue: reconstruct h64 in fp32 ---------------------------------
    #pragma unroll
    for (int rep = 0; rep < 2; ++rep) {
        int idx = t + rep * 512;                 // 1024 values
        int b = idx >> 6, k = idx & 63;
        h2tmp[idx] = (float)Act[cur][0][b][20 + k] + (float)Act[cur][1][b][20 + k];
    }
    __syncthreads();

    // ---- LSTM2 (single step, h=c=0 -> f-gate irrelevant) -------------------
    // u = t&255; thread half (t>>8) covers batches half*8..half*8+7
    {
        const int u = t & 255;
        const int bh0 = (t >> 8) * 8;
        float acci[8], accg[8], acco[8];
        float bi2 = b2[u], bg2 = b2[512 + u], bo2 = b2[768 + u];
        #pragma unroll
        for (int b = 0; b < 8; ++b) { acci[b] = bi2; accg[b] = bg2; acco[b] = bo2; }
        for (int k4 = 0; k4 < 64; k4 += 4) {
            float4 wi = *(const float4*)&Wih2[(size_t)u * 64 + k4];
            float4 wg = *(const float4*)&Wih2[(size_t)(512 + u) * 64 + k4];
            float4 wo = *(const float4*)&Wih2[(size_t)(768 + u) * 64 + k4];
            #pragma unroll
            for (int b = 0; b < 8; ++b) {
                float4 hb = *(const float4*)&h2tmp[(bh0 + b) * 64 + k4];
                acci[b] += wi.x * hb.x + wi.y * hb.y + wi.z * hb.z + wi.w * hb.w;
                accg[b] += wg.x * hb.x + wg.y * hb.y + wg.z * hb.z + wg.w * hb.w;
                acco[b] += wo.x * hb.x + wo.y * hb.y + wo.z * hb.z + wo.w * hb.w;
            }
        }
        #pragma unroll
        for (int b = 0; b < 8; ++b) {
            float c2 = sig_(acci[b]) * tanh_(accg[b]);
            h2s[u * BT + bh0 + b] = sig_(acco[b]) * tanh_(c2);
        }
    }
    __syncthreads();

    // ---- output projection -------------------------------------------------
    {
        int b = t & 15, grp = t >> 4;            // 32 groups x 8 units
        float p0 = 0.f, p1 = 0.f;
        for (int uu = grp * 8; uu < grp * 8 + 8; ++uu) {
            float hvv = h2s[uu * BT + b];
            p0 += hvv * Wout[uu];
            p1 += hvv * Wout[256 + uu];
        }
        part[(grp * BT + b) * 2 + 0] = p0;
        part[(grp * BT + b) * 2 + 1] = p1;
    }
    __syncthreads();
    if (t < 32) {
        int b = t >> 1, o = t & 1;
        float s0 = bout[o];
        for (int grp = 0; grp < 32; ++grp) s0 += part[(grp * BT + b) * 2 + o];
        out[(size_t)(b0 + b) * 2 + o] = s0;
    }
}

extern "C" void kernel_launch(void* const* d_in, const int* in_sizes, int n_in,
                              void* d_out, int out_size, void* d_ws, size_t ws_size,
                              hipStream_t stream) {
    const float* x    = (const float*)d_in[0];
    const float* Wemb = (const float*)d_in[1];
    const float* Wih1 = (const float*)d_in[2];
    const float* Whh1 = (const float*)d_in[3];
    const float* b1   = (const float*)d_in[4];
    const float* Wih2 = (const float*)d_in[5];
    // d_in[6] = Whh2: unused (h=c=0 at LSTM2's single step)
    const float* b2   = (const float*)d_in[7];
    const float* Wout = (const float*)d_in[8];
    const float* bout = (const float*)d_in[9];
    float* out = (float*)d_out;

    lstm_mfma_kernel<<<256, 512, 0, stream>>>(
        x, Wemb, Wih1, Whh1, b1, Wih2, b2, Wout, bout, out);
}

// Round 6
// 413.569 us; speedup vs baseline: 6.0613x; 1.1703x over previous
//
#include <hip/hip_runtime.h>

typedef _Float16 f16x8 __attribute__((ext_vector_type(8)));
typedef float    f32x4 __attribute__((ext_vector_type(4)));

#define NSTEP 512
#define BT 16       // batches per block = full MFMA tile width
#define KS 104      // Act row stride in f16 (52 dw; 52%32=20 -> conflict-benign)

__device__ __forceinline__ float sig_(float v) {
    return __builtin_amdgcn_rcpf(1.0f + __expf(-v));
}
// clamped (e-1)/(e+1) form — lowest measured error (R4: absmax 1.5e-5)
__device__ __forceinline__ float tanh_(float v) {
    v = fminf(fmaxf(v, -15.0f), 15.0f);
    float e = __expf(v + v);
    return (e - 1.0f) * __builtin_amdgcn_rcpf(e + 1.0f);
}

// 512 threads = 8 waves, grid 256 (1 block/CU, 2 waves/SIMD), 16 batches/block.
// Gate matrix (256 rows = gate*64+unit) tiled as 16 MFMA tiles, tile tau covers
// units tau*4..+3, tile-row = usub*4 + gate -> all 4 gates of a unit in one lane
// (acc[r] = gate r). Wave w owns tiles {2w, 2w+1}.
// Precision: f16 2-pass, WEIGHT-only split: W = Whi + Wlo*2^-11 (Wlo prescaled
// x2048, f16-normal). Activations: single f16 copy (A-quant 2^-12 noise, damped
// by gate slopes + f-gate decay). Two INDEPENDENT MFMA chains (Whi, Wlo), one
// scaled-fma combine. Halves LDS traffic and cuts MFMA 18->12 vs bf16 3-pass.
__global__ __launch_bounds__(512, 2) void lstm_mfma_kernel(
    const float* __restrict__ x,     const float* __restrict__ Wemb,
    const float* __restrict__ Wih1,  const float* __restrict__ Whh1,
    const float* __restrict__ b1,    const float* __restrict__ Wih2,
    const float* __restrict__ b2,    const float* __restrict__ Wout,
    const float* __restrict__ bout,  float* __restrict__ out)
{
    __shared__ __align__(16) _Float16 Act[2][16][KS];   // [buf][batch][k]  6656 B
    __shared__ __align__(16) float h2tmp[BT * 64];      //                  4096 B
    __shared__ __align__(16) float h2s[256 * BT];       //                 16384 B
    __shared__ float part[32 * BT * 2];                 //                  4096 B

    const int t = threadIdx.x;
    const int l = t & 63;
    const int w = t >> 6;        // wave 0..7
    const int m = l & 15;        // tile A-row / B col (batch) / D col
    const int q = l >> 4;        // quad: D rows q*4+r
    const int b0 = blockIdx.x * BT;

    // ---- one-time: weight fragments (f16 hi + lo*2048) into registers ------
    f16x8 wh[2][3], wl[2][3];
    #pragma unroll
    for (int tt = 0; tt < 2; ++tt) {
        const int n = (m & 3) * 64 + (2 * w + tt) * 4 + (m >> 2);  // gate-row
        #pragma unroll
        for (int kc = 0; kc < 3; ++kc) {
            #pragma unroll
            for (int jj = 0; jj < 8; ++jj) {
                int k = kc * 32 + (q << 3) + jj;
                float v = 0.0f;
                if (k < 20)       v = Wih1[n * 20 + k];
                else if (k < 84)  v = Whh1[n * 64 + (k - 20)];
                _Float16 hi = (_Float16)v;
                wh[tt][kc][jj] = hi;
                wl[tt][kc][jj] = (_Float16)((v - (float)hi) * 2048.0f);
            }
        }
    }
    // lane's units: u(tt) = (2w+tt)*4 + q; bias vector = b1[r*64 + u]
    f32x4 bias[2];
    #pragma unroll
    for (int tt = 0; tt < 2; ++tt)
        #pragma unroll
        for (int r = 0; r < 4; ++r)
            bias[tt][r] = b1[r * 64 + (2 * w + tt) * 4 + q];

    // ---- emb-writer role: t<320 covers (be=t&15, ee=t>>4), ee 0..19 --------
    const int be = t & 15;
    const int ee = t >> 4;
    const bool embp = (t < 320);
    const float* xrow = x + (size_t)(b0 + be) * (2 * NSTEP);
    float we0 = 0.f, we1 = 0.f;
    if (embp) { we0 = Wemb[ee * 2]; we1 = Wemb[ee * 2 + 1]; }

    // ---- zero Act (k pads 84..103 stay zero), emb of token 0 ---------------
    for (int idx = t; idx < 2 * 16 * KS; idx += 512)
        ((_Float16*)Act)[idx] = (_Float16)0.0f;
    __syncthreads();
    if (embp) {
        float x0 = xrow[0], x1 = xrow[1];
        Act[0][be][ee] = (_Float16)fmaxf(x0 * we0 + x1 * we1, 0.0f);
    }
    __syncthreads();

    // ---- main recurrence ---------------------------------------------------
    float cst[2] = {0.f, 0.f};
    int cur = 0;

    for (int step = 0; step < NSTEP; ++step) {
        // prefetch next token (L2-resident)
        float xa = 0.f, xb = 0.f;
        if (embp) {
            int ns = (step + 1 < NSTEP) ? step + 1 : NSTEP - 1;
            xa = xrow[2 * ns]; xb = xrow[2 * ns + 1];
        }

        // B-frags: lane holds Act[batch=m][k=kc*32+q*8+jj] (single f16 copy)
        f16x8 bfr[3];
        #pragma unroll
        for (int kc = 0; kc < 3; ++kc)
            bfr[kc] = *(const f16x8*)&Act[cur][m][kc * 32 + (q << 3)];

        f32x4 a0[2], a1[2];
        #pragma unroll
        for (int tt = 0; tt < 2; ++tt) {
            a0[tt] = bias[tt];
            a1[tt] = (f32x4){0.f, 0.f, 0.f, 0.f};
        }
        // two independent chains per tile (hi, lo), interleaved issue
        #pragma unroll
        for (int tt = 0; tt < 2; ++tt) {
            #pragma unroll
            for (int kc = 0; kc < 3; ++kc) {
                a0[tt] = __builtin_amdgcn_mfma_f32_16x16x32_f16(wh[tt][kc], bfr[kc], a0[tt], 0, 0, 0);
                a1[tt] = __builtin_amdgcn_mfma_f32_16x16x32_f16(wl[tt][kc], bfr[kc], a1[tt], 0, 0, 0);
            }
        }

        // activations: lane owns (unit u(tt), batch m); gates = a0 + 2^-11*a1
        const int nxt = cur ^ 1;
        #pragma unroll
        for (int tt = 0; tt < 2; ++tt) {
            float gi = a0[tt][0] + 0x1p-11f * a1[tt][0];
            float gf = a0[tt][1] + 0x1p-11f * a1[tt][1];
            float gg = a0[tt][2] + 0x1p-11f * a1[tt][2];
            float go = a0[tt][3] + 0x1p-11f * a1[tt][3];
            float ig = sig_(gi);
            float fg = sig_(gf);
            float gv = tanh_(gg);
            float og = sig_(go);
            cst[tt] = fg * cst[tt] + ig * gv;
            float hv = og * tanh_(cst[tt]);
            Act[nxt][m][20 + (2 * w + tt) * 4 + q] = (_Float16)hv;
        }
        // emb for next step
        if (embp)
            Act[nxt][be][ee] = (_Float16)fmaxf(xa * we0 + xb * we1, 0.0f);
        __syncthreads();
        cur = nxt;
    }
    // final h (f16) in Act[cur]

    // ---- epilogue: h64 to fp32 ---------------------------------------------
    #pragma unroll
    for (int rep = 0; rep < 2; ++rep) {
        int idx = t + rep * 512;                 // 1024 values
        int b = idx >> 6, k = idx & 63;
        h2tmp[idx] = (float)Act[cur][b][20 + k];
    }
    __syncthreads();

    // ---- LSTM2 (single step, h=c=0 -> f-gate irrelevant) -------------------
    {
        const int u = t & 255;
        const int bh0 = (t >> 8) * 8;
        float acci[8], accg[8], acco[8];
        float bi2 = b2[u], bg2 = b2[512 + u], bo2 = b2[768 + u];
        #pragma unroll
        for (int b = 0; b < 8; ++b) { acci[b] = bi2; accg[b] = bg2; acco[b] = bo2; }
        for (int k4 = 0; k4 < 64; k4 += 4) {
            float4 wi = *(const float4*)&Wih2[(size_t)u * 64 + k4];
            float4 wg = *(const float4*)&Wih2[(size_t)(512 + u) * 64 + k4];
            float4 wo = *(const float4*)&Wih2[(size_t)(768 + u) * 64 + k4];
            #pragma unroll
            for (int b = 0; b < 8; ++b) {
                float4 hb = *(const float4*)&h2tmp[(bh0 + b) * 64 + k4];
                acci[b] += wi.x * hb.x + wi.y * hb.y + wi.z * hb.z + wi.w * hb.w;
                accg[b] += wg.x * hb.x + wg.y * hb.y + wg.z * hb.z + wg.w * hb.w;
                acco[b] += wo.x * hb.x + wo.y * hb.y + wo.z * hb.z + wo.w * hb.w;
            }
        }
        #pragma unroll
        for (int b = 0; b < 8; ++b) {
            float c2 = sig_(acci[b]) * tanh_(accg[b]);
            h2s[u * BT + bh0 + b] = sig_(acco[b]) * tanh_(c2);
        }
    }
    __syncthreads();

    // ---- output projection -------------------------------------------------
    {
        int b = t & 15, grp = t >> 4;            // 32 groups x 8 units
        float p0 = 0.f, p1 = 0.f;
        for (int uu = grp * 8; uu < grp * 8 + 8; ++uu) {
            float hvv = h2s[uu * BT + b];
            p0 += hvv * Wout[uu];
            p1 += hvv * Wout[256 + uu];
        }
        part[(grp * BT + b) * 2 + 0] = p0;
        part[(grp * BT + b) * 2 + 1] = p1;
    }
    __syncthreads();
    if (t < 32) {
        int b = t >> 1, o = t & 1;
        float s0 = bout[o];
        for (int grp = 0; grp < 32; ++grp) s0 += part[(grp * BT + b) * 2 + o];
        out[(size_t)(b0 + b) * 2 + o] = s0;
    }
}

extern "C" void kernel_launch(void* const* d_in, const int* in_sizes, int n_in,
                              void* d_out, int out_size, void* d_ws, size_t ws_size,
                              hipStream_t stream) {
    const float* x    = (const float*)d_in[0];
    const float* Wemb = (const float*)d_in[1];
    const float* Wih1 = (const float*)d_in[2];
    const float* Whh1 = (const float*)d_in[3];
    const float* b1   = (const float*)d_in[4];
    const float* Wih2 = (const float*)d_in[5];
    // d_in[6] = Whh2: unused (h=c=0 at LSTM2's single step)
    const float* b2   = (const float*)d_in[7];
    const float* Wout = (const float*)d_in[8];
    const float* bout = (const float*)d_in[9];
    float* out = (float*)d_out;

    lstm_mfma_kernel<<<256, 512, 0, stream>>>(
        x, Wemb, Wih1, Whh1, b1, Wih2, b2, Wout, bout, out);
}